// Round 1
// baseline (483.596 us; speedup 1.0000x reference)
//
#include <hip/hip_runtime.h>

// LocalExpansion: out[b,h,(y,x),c,d] = in[b,h,(y+i-3,x+j-3),d], c = i*7+j,
// zero-filled outside the image. Pure gather+write, memory-bound on the
// 462 MB output write.

#define KH 7
#define KW 7
#define HEIGHT 48
#define WIDTH 48
#define DDIM 64
#define NPIX (HEIGHT * WIDTH)   // 2304
#define KK (KH * KW)            // 49

__global__ __launch_bounds__(256) void local_expansion_kernel(
    const float* __restrict__ in, float* __restrict__ out) {
    // One thread per output float4. Grid sized exactly: total4 % 256 == 0.
    int idx4 = blockIdx.x * 256 + threadIdx.x;

    // idx4 = ((bh * NPIX + n) * KK + c) * 16 + d4
    int d4   = idx4 & 15;
    int rem  = idx4 >> 4;        // (bh*NPIX + n)*KK + c
    int c    = rem % KK;
    int rem2 = rem / KK;         // bh*NPIX + n
    int n    = rem2 % NPIX;
    int bh   = rem2 / NPIX;

    int y = n / WIDTH;
    int x = n - y * WIDTH;
    int i = c / KW;
    int j = c - i * KW;

    int sy = y + i - (KH - 1) / 2;
    int sx = x + j - (KW - 1) / 2;

    float4 v = make_float4(0.f, 0.f, 0.f, 0.f);
    if ((unsigned)sy < (unsigned)HEIGHT && (unsigned)sx < (unsigned)WIDTH) {
        int in4 = (bh * NPIX + sy * WIDTH + sx) * (DDIM / 4) + d4;
        v = ((const float4*)in)[in4];
    }
    ((float4*)out)[idx4] = v;
}

extern "C" void kernel_launch(void* const* d_in, const int* in_sizes, int n_in,
                              void* d_out, int out_size, void* d_ws, size_t ws_size,
                              hipStream_t stream) {
    const float* x = (const float*)d_in[0];
    float* out = (float*)d_out;

    // out_size = 2*8*2304*49*64 = 115,605,504 floats -> 28,901,376 float4s
    int total4 = out_size / 4;
    dim3 grid(total4 / 256);   // 112,896 blocks, exact
    local_expansion_kernel<<<grid, 256, 0, stream>>>(x, out);
}